// Round 5
// baseline (233.576 us; speedup 1.0000x reference)
//
#include <hip/hip_runtime.h>
#include <hip/hip_bf16.h>

// B=8,G=16,N=1024,C=256.
// R10: single-shot full-width blocks.
//  Grid = (bg, nt) = 128*16 = 2048 blocks x 512 threads (8 waves).
//  Each block: stage full 64x256 x-tile once (fp32->bf16 LDS, coalesced),
//  ONE lgkm-only barrier, then each wave computes a disjoint 32-col strip
//  over full K=256 (64 MFMAs; B-frags JIT from L2-hot fragment-major WbT,
//  coalesced, no barriers in the MFMA region -> compiler pipelines them).
//  Phase B (exp/Z/S) reads the same LDS tile. Halves x traffic + cvt work
//  vs R9's col-half split (each tile was read twice), removes chunk-B chain.
// wfc_cvt / vn_linear / ws layout unchanged from R9 (passing).

#define NQ 1024
#define CQ 256
#define RT 64           // rows per block (one n-tile)
#define XS2 264         // xs row stride (bf16 elems): 528 B (16B-mult; 2-way bank alias only)
#define WB_OFF 131072   // ws float offset of bf16 Wfc (after 512 KB partials)

typedef __attribute__((ext_vector_type(8))) short bf16x8;
typedef __attribute__((ext_vector_type(4))) float f32x4;

__device__ __forceinline__ ushort2 pk2(float a, float b) {
    __hip_bfloat162 h = __float22bfloat162_rn(make_float2(a, b));  // v_cvt_pk_bf16_f32
    ushort2 r;
    __builtin_memcpy(&r, &h, sizeof(r));
    return r;
}
__device__ __forceinline__ float bf2f(ushort h) {
    union { unsigned u; float f; } v; v.u = ((unsigned)h) << 16;
    return v.f;
}

// lgkm-only barrier: LDS writes visible, global loads stay in flight.
__device__ __forceinline__ void bar_lgkm() {
    __builtin_amdgcn_sched_barrier(0);
    asm volatile("s_waitcnt lgkmcnt(0)" ::: "memory");
    __builtin_amdgcn_sched_barrier(0);
    __builtin_amdgcn_s_barrier();
    __builtin_amdgcn_sched_barrier(0);
}

// ---- kernel 1: Wfc fp32 -> bf16 fragment-major WbT[k>>3][col][k&7] ----
__global__ __launch_bounds__(256)
void wfc_cvt(const float* __restrict__ Wfc, ushort* __restrict__ WbT) {
    const int i = blockIdx.x * 256 + threadIdx.x;   // 16384 threads x 4 floats
    const int o = i >> 6;            // output col (Wfc row) 0..255
    const int k4 = (i & 63) * 4;     // k start 0..252
    float4 v = *reinterpret_cast<const float4*>(Wfc + (size_t)o * CQ + k4);
    ushort2 a0 = pk2(v.x, v.y), a1 = pk2(v.z, v.w);
    ushort4 pk = { a0.x, a0.y, a1.x, a1.y };
    *reinterpret_cast<ushort4*>(WbT + ((size_t)(k4 >> 3) * CQ + o) * 8 + (k4 & 7)) = pk;
}

// ---- kernel 2: fused q=x@Wfc^T, e=exp(q), partial Z/S accumulation ----
__global__ __launch_bounds__(512, 4)
void attn_pool_partial(const float* __restrict__ x, const float* __restrict__ vs,
                       const ushort* __restrict__ WbT, float* __restrict__ ws) {
    __shared__ __align__(16) ushort xs[RT * XS2];  // 33792 B: full 64x256 tile (bf16)
    __shared__ __align__(16) float  vsm[RT * 3];   // 768 B

    const int t = threadIdx.x;                     // 0..511
    const int id = blockIdx.x;
    const int bg = id >> 4;
    const int nt = id & 15;
    const int n0 = nt * RT;

    const int w = t >> 6, lane = t & 63;
    const int quad = lane >> 4, l16 = lane & 15;
    const int bcol0 = w * 32 + l16;                // wave w owns cols w*32..w*32+31

    const float* xb = x + (size_t)bg * NQ * CQ;
    const float* vb = vs + (size_t)bg * NQ * 3;

    // ---- upfront global issue: v, then the full x tile (8 float4/thread) ----
    const bool vload = (t < 48);
    float4 vreg;
    if (vload) vreg = reinterpret_cast<const float4*>(vb + (size_t)n0 * 3)[t];
    __builtin_amdgcn_sched_barrier(0);

    float4 LA[8];
    #pragma unroll
    for (int p = 0; p < 8; ++p) {
        const int idx = p * 512 + t;               // 0..4095 float4s
        const int row = idx >> 6, k4 = idx & 63;
        LA[p] = *reinterpret_cast<const float4*>(
            xb + (size_t)(n0 + row) * CQ + k4 * 4);
    }
    __builtin_amdgcn_sched_barrier(0);

    // ---- cvt + LDS write (counted wait on x-loads only) ----
    #pragma unroll
    for (int p = 0; p < 8; ++p) {
        const int idx = p * 512 + t;
        const int row = idx >> 6, k4 = idx & 63;
        ushort2 a0 = pk2(LA[p].x, LA[p].y), a1 = pk2(LA[p].z, LA[p].w);
        ushort4 pk = { a0.x, a0.y, a1.x, a1.y };
        *reinterpret_cast<ushort4*>(&xs[row * XS2 + k4 * 4]) = pk;
    }
    if (vload) reinterpret_cast<float4*>(vsm)[t] = vreg;

    bar_lgkm();   // the ONLY barrier: xs + vsm visible

    f32x4 acc[4][2];
    #pragma unroll
    for (int m = 0; m < 4; ++m)
        #pragma unroll
        for (int ci = 0; ci < 2; ++ci) acc[m][ci] = (f32x4){0.f, 0.f, 0.f, 0.f};

    // ---- MFMA over full K=256; B-frags JIT (coalesced fragment-major, L2-hot) ----
    __builtin_amdgcn_s_setprio(1);
    #pragma unroll
    for (int ks = 0; ks < 8; ++ks) {
        const int kk = ks * 32 + quad * 8;
        const size_t fo = (size_t)(ks * 4 + quad) * (CQ * 8);
        bf16x8 b0 = *reinterpret_cast<const bf16x8*>(WbT + fo + (size_t)bcol0 * 8);
        bf16x8 b1 = *reinterpret_cast<const bf16x8*>(WbT + fo + (size_t)(bcol0 + 16) * 8);
        #pragma unroll
        for (int m = 0; m < 4; ++m) {
            bf16x8 a = *reinterpret_cast<const bf16x8*>(&xs[(m * 16 + l16) * XS2 + kk]);
            acc[m][0] = __builtin_amdgcn_mfma_f32_16x16x32_bf16(a, b0, acc[m][0], 0, 0, 0);
            acc[m][1] = __builtin_amdgcn_mfma_f32_16x16x32_bf16(a, b1, acc[m][1], 0, 0, 0);
        }
    }
    __builtin_amdgcn_s_setprio(0);

    // ---- phase B: e = exp(q); accumulate partial Z, S over this tile's 64 rows ----
    float rZ[2] = {0.f, 0.f}, rS0[2] = {0.f, 0.f}, rS1[2] = {0.f, 0.f}, rS2[2] = {0.f, 0.f};
    #pragma unroll
    for (int m = 0; m < 4; ++m) {
        const int rbase = m * 16 + quad * 4;
        float v0[4], v1[4], v2[4];
        #pragma unroll
        for (int r = 0; r < 4; ++r) {
            v0[r] = vsm[(rbase + r) * 3 + 0];
            v1[r] = vsm[(rbase + r) * 3 + 1];
            v2[r] = vsm[(rbase + r) * 3 + 2];
        }
        #pragma unroll
        for (int ci = 0; ci < 2; ++ci) {
            const int xc = w * 32 + ci * 16 + l16;
            #pragma unroll
            for (int r = 0; r < 4; ++r) {
                float e = __expf(acc[m][ci][r]);
                float xv = bf2f(xs[(rbase + r) * XS2 + xc]);
                rZ[ci] += e;
                float p = e * xv;
                rS0[ci] = fmaf(p, v0[r], rS0[ci]);
                rS1[ci] = fmaf(p, v1[r], rS1[ci]);
                rS2[ci] = fmaf(p, v2[r], rS2[ci]);
            }
        }
    }

    // ---- reduce over quads (each wave owns disjoint cols) and atomicAdd partials ----
    #pragma unroll
    for (int ci = 0; ci < 2; ++ci) {
        float z = rZ[ci], s0 = rS0[ci], s1 = rS1[ci], s2 = rS2[ci];
        #pragma unroll
        for (int off = 16; off < 64; off <<= 1) {
            z  += __shfl_xor(z,  off);
            s0 += __shfl_xor(s0, off);
            s1 += __shfl_xor(s1, off);
            s2 += __shfl_xor(s2, off);
        }
        if (quad == 0) {
            const int col = w * 32 + ci * 16 + l16;
            float* p = ws + ((size_t)bg * CQ + col) * 4;
            atomicAdd(&p[0], z);
            atomicAdd(&p[1], s0);
            atomicAdd(&p[2], s1);
            atomicAdd(&p[3], s2);
        }
    }
}

// ---- kernel 3: out[bg][o][d] = sum_c Wvn[o][c] * S[bg][c][d] / Z[bg][c] ----
__global__ __launch_bounds__(256, 4)
void vn_linear(const float* __restrict__ ws, const float* __restrict__ Wvn,
               float* __restrict__ out) {
    __shared__ float Tsm[CQ][3];
    const int bg = blockIdx.x, t = threadIdx.x;
    {
        f32x4 z4 = *reinterpret_cast<const f32x4*>(ws + ((size_t)bg * CQ + t) * 4);
        float inv = 1.f / z4[0];
        Tsm[t][0] = z4[1] * inv;
        Tsm[t][1] = z4[2] * inv;
        Tsm[t][2] = z4[3] * inv;
    }
    __syncthreads();
    const float* wr = Wvn + (size_t)t * CQ;
    float a0 = 0.f, a1 = 0.f, a2 = 0.f;
    #pragma unroll
    for (int c = 0; c < CQ; c += 4) {
        float4 w4 = *reinterpret_cast<const float4*>(wr + c);
        a0 += w4.x * Tsm[c + 0][0] + w4.y * Tsm[c + 1][0]
            + w4.z * Tsm[c + 2][0] + w4.w * Tsm[c + 3][0];
        a1 += w4.x * Tsm[c + 0][1] + w4.y * Tsm[c + 1][1]
            + w4.z * Tsm[c + 2][1] + w4.w * Tsm[c + 3][1];
        a2 += w4.x * Tsm[c + 0][2] + w4.y * Tsm[c + 1][2]
            + w4.z * Tsm[c + 2][2] + w4.w * Tsm[c + 3][2];
    }
    float* op = out + ((size_t)bg * CQ + t) * 3;
    op[0] = a0; op[1] = a1; op[2] = a2;
}

extern "C" void kernel_launch(void* const* d_in, const int* in_sizes, int n_in,
                              void* d_out, int out_size, void* d_ws, size_t ws_size,
                              hipStream_t stream) {
    const float* x   = (const float*)d_in[0];  // [8,16,1024,256]
    const float* vs  = (const float*)d_in[1];  // [8,16,1,1024,3]
    const float* Wfc = (const float*)d_in[2];  // [256,256]
    // d_in[3] = b_fc: constant along softmax axis n -> no effect, unused
    const float* Wvn = (const float*)d_in[4];  // [256,256]
    float* out = (float*)d_out;                // [8,16,256,3]
    float* ws  = (float*)d_ws;                 // 512 KB partials + 128 KB bf16 Wfc

    ushort* WbT = (ushort*)(ws + WB_OFF);

    (void)hipMemsetAsync(ws, 0, (size_t)128 * CQ * 4 * sizeof(float), stream);
    wfc_cvt<<<dim3(64), dim3(256), 0, stream>>>(Wfc, WbT);
    attn_pool_partial<<<dim3(2048), dim3(512), 0, stream>>>(x, vs, WbT, ws);
    vn_linear<<<dim3(128), dim3(256), 0, stream>>>(ws, Wvn, out);
}

// Round 6
// 217.062 us; speedup vs baseline: 1.0761x; 1.0761x over previous
//
#include <hip/hip_runtime.h>
#include <hip/hip_bf16.h>

// B=8,G=16,N=1024,C=256.
// R11: R10 single-shot structure + R9's fenced early-issue for B-fragments.
//  R10's VGPR=48 proved the compiler kept JIT B-loads inside the MFMA loop
//  (2 at a time, vmcnt(0) each -> 8 serial L2 stalls on the MFMA chain).
//  Fix: pin issue order with sched_barrier(0): v(1), x-tile LA(8), B(16).
//  In-order vmcnt retirement => cvt's counted wait on LA leaves B in flight;
//  MFMA consumes B already-arrived. Peak live ~115 VGPR < 128 cap (512,4).
//  Grid = (bg, nt) = 2048 blocks x 512 thr; one lgkm-only barrier per block.
// wfc_cvt / vn_linear / ws layout unchanged (passing since R7).

#define NQ 1024
#define CQ 256
#define RT 64           // rows per block (one n-tile)
#define XS2 264         // xs row stride (bf16 elems): 528 B (16B-mult)
#define WB_OFF 131072   // ws float offset of bf16 Wfc (after 512 KB partials)

typedef __attribute__((ext_vector_type(8))) short bf16x8;
typedef __attribute__((ext_vector_type(4))) float f32x4;

__device__ __forceinline__ ushort2 pk2(float a, float b) {
    __hip_bfloat162 h = __float22bfloat162_rn(make_float2(a, b));  // v_cvt_pk_bf16_f32
    ushort2 r;
    __builtin_memcpy(&r, &h, sizeof(r));
    return r;
}
__device__ __forceinline__ float bf2f(ushort h) {
    union { unsigned u; float f; } v; v.u = ((unsigned)h) << 16;
    return v.f;
}

// lgkm-only barrier: LDS writes visible, global loads stay in flight.
__device__ __forceinline__ void bar_lgkm() {
    __builtin_amdgcn_sched_barrier(0);
    asm volatile("s_waitcnt lgkmcnt(0)" ::: "memory");
    __builtin_amdgcn_sched_barrier(0);
    __builtin_amdgcn_s_barrier();
    __builtin_amdgcn_sched_barrier(0);
}

// ---- kernel 1: Wfc fp32 -> bf16 fragment-major WbT[k>>3][col][k&7] ----
__global__ __launch_bounds__(256)
void wfc_cvt(const float* __restrict__ Wfc, ushort* __restrict__ WbT) {
    const int i = blockIdx.x * 256 + threadIdx.x;   // 16384 threads x 4 floats
    const int o = i >> 6;            // output col (Wfc row) 0..255
    const int k4 = (i & 63) * 4;     // k start 0..252
    float4 v = *reinterpret_cast<const float4*>(Wfc + (size_t)o * CQ + k4);
    ushort2 a0 = pk2(v.x, v.y), a1 = pk2(v.z, v.w);
    ushort4 pk = { a0.x, a0.y, a1.x, a1.y };
    *reinterpret_cast<ushort4*>(WbT + ((size_t)(k4 >> 3) * CQ + o) * 8 + (k4 & 7)) = pk;
}

// ---- kernel 2: fused q=x@Wfc^T, e=exp(q), partial Z/S accumulation ----
__global__ __launch_bounds__(512, 4)
void attn_pool_partial(const float* __restrict__ x, const float* __restrict__ vs,
                       const ushort* __restrict__ WbT, float* __restrict__ ws) {
    __shared__ __align__(16) ushort xs[RT * XS2];  // 33792 B: full 64x256 tile (bf16)
    __shared__ __align__(16) float  vsm[RT * 3];   // 768 B

    const int t = threadIdx.x;                     // 0..511
    const int id = blockIdx.x;
    const int bg = id >> 4;
    const int nt = id & 15;
    const int n0 = nt * RT;

    const int w = t >> 6, lane = t & 63;
    const int quad = lane >> 4, l16 = lane & 15;
    const int bcol0 = w * 32 + l16;                // wave w owns cols w*32..w*32+31

    const float* xb = x + (size_t)bg * NQ * CQ;
    const float* vb = vs + (size_t)bg * NQ * 3;

    // ---- group 0: v (issued first; drained by any later counted wait) ----
    const bool vload = (t < 48);
    float4 vreg;
    if (vload) vreg = reinterpret_cast<const float4*>(vb + (size_t)n0 * 3)[t];
    __builtin_amdgcn_sched_barrier(0);

    // ---- group 1: full x tile, 8 float4/thread (coalesced) ----
    float4 LA[8];
    #pragma unroll
    for (int p = 0; p < 8; ++p) {
        const int idx = p * 512 + t;               // 0..4095 float4s
        const int row = idx >> 6, k4 = idx & 63;
        LA[p] = *reinterpret_cast<const float4*>(
            xb + (size_t)(n0 + row) * CQ + k4 * 4);
    }
    __builtin_amdgcn_sched_barrier(0);

    // ---- group 2: ALL 16 B-fragments (coalesced fragment-major, L2-hot).
    //      Issued last: cvt's counted wait on LA leaves these in flight. ----
    bf16x8 Bf0[8], Bf1[8];
    #pragma unroll
    for (int ks = 0; ks < 8; ++ks) {
        const size_t fo = (size_t)(ks * 4 + quad) * (CQ * 8);
        Bf0[ks] = *reinterpret_cast<const bf16x8*>(WbT + fo + (size_t)bcol0 * 8);
        Bf1[ks] = *reinterpret_cast<const bf16x8*>(WbT + fo + (size_t)(bcol0 + 16) * 8);
    }
    __builtin_amdgcn_sched_barrier(0);

    // ---- cvt + LDS write (counted wait on v+LA only; B stays in flight) ----
    #pragma unroll
    for (int p = 0; p < 8; ++p) {
        const int idx = p * 512 + t;
        const int row = idx >> 6, k4 = idx & 63;
        ushort2 a0 = pk2(LA[p].x, LA[p].y), a1 = pk2(LA[p].z, LA[p].w);
        ushort4 pk = { a0.x, a0.y, a1.x, a1.y };
        *reinterpret_cast<ushort4*>(&xs[row * XS2 + k4 * 4]) = pk;
    }
    if (vload) reinterpret_cast<float4*>(vsm)[t] = vreg;

    bar_lgkm();   // the ONLY barrier: xs + vsm visible; B-frags still in flight

    f32x4 acc[4][2];
    #pragma unroll
    for (int m = 0; m < 4; ++m)
        #pragma unroll
        for (int ci = 0; ci < 2; ++ci) acc[m][ci] = (f32x4){0.f, 0.f, 0.f, 0.f};

    // ---- MFMA over full K=256 (B-frags already resident/in-flight) ----
    __builtin_amdgcn_s_setprio(1);
    #pragma unroll
    for (int ks = 0; ks < 8; ++ks) {
        const int kk = ks * 32 + quad * 8;
        #pragma unroll
        for (int m = 0; m < 4; ++m) {
            bf16x8 a = *reinterpret_cast<const bf16x8*>(&xs[(m * 16 + l16) * XS2 + kk]);
            acc[m][0] = __builtin_amdgcn_mfma_f32_16x16x32_bf16(a, Bf0[ks], acc[m][0], 0, 0, 0);
            acc[m][1] = __builtin_amdgcn_mfma_f32_16x16x32_bf16(a, Bf1[ks], acc[m][1], 0, 0, 0);
        }
    }
    __builtin_amdgcn_s_setprio(0);

    // ---- phase B: e = exp(q); accumulate partial Z, S over this tile's 64 rows ----
    float rZ[2] = {0.f, 0.f}, rS0[2] = {0.f, 0.f}, rS1[2] = {0.f, 0.f}, rS2[2] = {0.f, 0.f};
    #pragma unroll
    for (int m = 0; m < 4; ++m) {
        const int rbase = m * 16 + quad * 4;
        float v0[4], v1[4], v2[4];
        #pragma unroll
        for (int r = 0; r < 4; ++r) {
            v0[r] = vsm[(rbase + r) * 3 + 0];
            v1[r] = vsm[(rbase + r) * 3 + 1];
            v2[r] = vsm[(rbase + r) * 3 + 2];
        }
        #pragma unroll
        for (int ci = 0; ci < 2; ++ci) {
            const int xc = w * 32 + ci * 16 + l16;
            #pragma unroll
            for (int r = 0; r < 4; ++r) {
                float e = __expf(acc[m][ci][r]);
                float xv = bf2f(xs[(rbase + r) * XS2 + xc]);
                rZ[ci] += e;
                float p = e * xv;
                rS0[ci] = fmaf(p, v0[r], rS0[ci]);
                rS1[ci] = fmaf(p, v1[r], rS1[ci]);
                rS2[ci] = fmaf(p, v2[r], rS2[ci]);
            }
        }
    }

    // ---- reduce over quads (each wave owns disjoint cols) and atomicAdd partials ----
    #pragma unroll
    for (int ci = 0; ci < 2; ++ci) {
        float z = rZ[ci], s0 = rS0[ci], s1 = rS1[ci], s2 = rS2[ci];
        #pragma unroll
        for (int off = 16; off < 64; off <<= 1) {
            z  += __shfl_xor(z,  off);
            s0 += __shfl_xor(s0, off);
            s1 += __shfl_xor(s1, off);
            s2 += __shfl_xor(s2, off);
        }
        if (quad == 0) {
            const int col = w * 32 + ci * 16 + l16;
            float* p = ws + ((size_t)bg * CQ + col) * 4;
            atomicAdd(&p[0], z);
            atomicAdd(&p[1], s0);
            atomicAdd(&p[2], s1);
            atomicAdd(&p[3], s2);
        }
    }
}

// ---- kernel 3: out[bg][o][d] = sum_c Wvn[o][c] * S[bg][c][d] / Z[bg][c] ----
__global__ __launch_bounds__(256, 4)
void vn_linear(const float* __restrict__ ws, const float* __restrict__ Wvn,
               float* __restrict__ out) {
    __shared__ float Tsm[CQ][3];
    const int bg = blockIdx.x, t = threadIdx.x;
    {
        f32x4 z4 = *reinterpret_cast<const f32x4*>(ws + ((size_t)bg * CQ + t) * 4);
        float inv = 1.f / z4[0];
        Tsm[t][0] = z4[1] * inv;
        Tsm[t][1] = z4[2] * inv;
        Tsm[t][2] = z4[3] * inv;
    }
    __syncthreads();
    const float* wr = Wvn + (size_t)t * CQ;
    float a0 = 0.f, a1 = 0.f, a2 = 0.f;
    #pragma unroll
    for (int c = 0; c < CQ; c += 4) {
        float4 w4 = *reinterpret_cast<const float4*>(wr + c);
        a0 += w4.x * Tsm[c + 0][0] + w4.y * Tsm[c + 1][0]
            + w4.z * Tsm[c + 2][0] + w4.w * Tsm[c + 3][0];
        a1 += w4.x * Tsm[c + 0][1] + w4.y * Tsm[c + 1][1]
            + w4.z * Tsm[c + 2][1] + w4.w * Tsm[c + 3][1];
        a2 += w4.x * Tsm[c + 0][2] + w4.y * Tsm[c + 1][2]
            + w4.z * Tsm[c + 2][2] + w4.w * Tsm[c + 3][2];
    }
    float* op = out + ((size_t)bg * CQ + t) * 3;
    op[0] = a0; op[1] = a1; op[2] = a2;
}

extern "C" void kernel_launch(void* const* d_in, const int* in_sizes, int n_in,
                              void* d_out, int out_size, void* d_ws, size_t ws_size,
                              hipStream_t stream) {
    const float* x   = (const float*)d_in[0];  // [8,16,1024,256]
    const float* vs  = (const float*)d_in[1];  // [8,16,1,1024,3]
    const float* Wfc = (const float*)d_in[2];  // [256,256]
    // d_in[3] = b_fc: constant along softmax axis n -> no effect, unused
    const float* Wvn = (const float*)d_in[4];  // [256,256]
    float* out = (float*)d_out;                // [8,16,256,3]
    float* ws  = (float*)d_ws;                 // 512 KB partials + 128 KB bf16 Wfc

    ushort* WbT = (ushort*)(ws + WB_OFF);

    (void)hipMemsetAsync(ws, 0, (size_t)128 * CQ * 4 * sizeof(float), stream);
    wfc_cvt<<<dim3(64), dim3(256), 0, stream>>>(Wfc, WbT);
    attn_pool_partial<<<dim3(2048), dim3(512), 0, stream>>>(x, vs, WbT, ws);
    vn_linear<<<dim3(128), dim3(256), 0, stream>>>(ws, Wvn, out);
}